// Round 5
// baseline (143.957 us; speedup 1.0000x reference)
//
#include <hip/hip_runtime.h>

// RFCM loss, fused single pass + finalize. B=2, K=4, D=H=W=128. Scalar out.
//
// mean(J1) = (1/(B*N)) * sum_{b,k} [ A_bk - Sim_bk^2 / Sm_bk ]
//   Sm=sum mem, Sim=sum mem*img, A=sum mem*img^2, mem=y_pred^2
// mean(J2) = (1/(B*N)) * sum_n [ Sm*Sbk - Sm^2 - sum_k m*bk + sum_k m^2 ]
//   bk = box27(mem_k) incl center, zero pad. s9 = 3x3 in-plane box sum.
//   Band decomposition per plane t (R13/R14 algebra, carried mp/sp/Mp/Sp):
//   diag band + prev band at step t; next band of t-1 emitted at t (gate
//   t>d0); epilog emits next band for plane d0+SD. Zero history at d0=0.
//
// R15: block-cooperative LDS staging, counted vmcnt, no full drains.
// Post-mortem of R10-R14: dur = FETCH/~1.2TB/s for EVERY variant
// (occupancy 8-16%, LDS-DMA vs register, 8B vs 16B, prefetch 1-3 deep all
// invariant); request traffic pinned at ~4 TB/s = ~6 B/cyc/CU. Model:
// per-CU outstanding-read-miss limit x RTT wall (writes exempt -> fill's
// 6.5 TB/s). Levers left: fewer miss lines + cheaper RTT mix.
//  - each wave stages its cluster's 10 rows (contiguous!) per plane with
//    5 x global_load_lds into [2][4][10][128] LDS dbuf (40 KB): every
//    line requested ONCE per block; vertical halo via LDS rows (no
//    shfl_xor, no halo loads). Requests 176->139 MB.
//  - raw s_barrier + counted WAIT_VM(5): the 5 GLDs of the NEXT plane
//    stay in flight across every barrier; zero mid-loop vmcnt(0) drains.
//    (Needed GLDs are always the oldest outstanding; counted waits stay
//    correct even if the compiler sinks/hoists img register loads.)
//  - SD=4 -> 1024 blocks = 4 blocks/CU (LDS 4x40KB=160KB exact), 16
//    waves/CU; barrier stalls of one block hide under the other three.
//  - XCD swizzle groups dsb (d-adjacent slabs) per XCD -> halo planes
//    L2-hit (RTT ~250 vs ~900+).
// Decision rule: >=42us null => cold-miss floor, roofline next round.
// NEVER __launch_bounds__ min-waves (R4/R6: VGPR=64 -> 240-330MB spills).

#define BB 2
#define KK 4
#define DD 128
#define HH 128
#define WW 128
#define PLANE (HH * WW)
#define CLS ((size_t)DD * PLANE)  // cluster stride (floats)
#define SD 4
#define NBD (DD / SD)    // 32
#define HR 8             // rows/block = 4 waves x 2 rows
#define NBH (HH / HR)    // 16
#define NT 256
#define NROW 10          // staged rows per plane (8 owned + 2 halo)

typedef const void __attribute__((address_space(1))) gvoid_t;
typedef void __attribute__((address_space(3))) svoid_t;
#define GLD(gp, lp) __builtin_amdgcn_global_load_lds((gvoid_t*)(gp), (svoid_t*)(lp), 16, 0, 0)
// wait vmcnt(N), leave lgkm(15)/exp(7) free: [3:0]vm_lo [6:4]exp [11:8]lgkm
#define WAIT_VM(N) __builtin_amdgcn_s_waitcnt(0x0F70 | (N))
#define BAR() __builtin_amdgcn_s_barrier()

__global__ __launch_bounds__(NT) void rfcm_main(
    const float* __restrict__ yp, const float* __restrict__ img,
    double* __restrict__ ws)
{
    __shared__ __align__(16) float sbuf[2][KK][NROW][WW];   // 40960 B

    const int tid  = threadIdx.x;
    const int wv   = tid >> 6;       // wave 0..3: stages cluster wv, owns rows 2wv,2wv+1
    const int L    = tid & 63;
    const int half = L >> 5;
    const int wl   = L & 31;
    const int c0   = wl << 2;        // 4 cols/lane

    // XCD swizzle: 4 consecutive dsb per XCD (d-halo planes L2-shared).
    const int bid = blockIdx.x;
    const int xcd = bid & 7;
    const int j   = bid >> 3;        // 0..127
    const int dsb = xcd * 4 + (j & 3);      // 0..31
    const int ht  = (j >> 2) & 15;          // 0..15
    const int b   = j >> 6;                 // 0..1

    const int d0 = dsb * SD;         // even
    const int h0 = ht * HR;
    const int r  = h0 + (wv << 1) + half;   // own row

    int rs = h0 - 1; rs = rs < 0 ? 0 : (rs > HH - 2 - NROW + 2 ? 118 : rs);  // clamp(h0-1,0,118)
    const float su = (r > 0)      ? 1.f : 0.f;
    const float sd = (r < HH - 1) ? 1.f : 0.f;
    const int sc  = r - rs;                               // own-row slot
    const int sm1 = (r > 0      ? r - 1 : 0)      - rs;   // up slot
    const int sp1 = (r < HH - 1 ? r + 1 : HH - 1) - rs;   // down slot

    const bool okL = (wl > 0), okR = (wl < 31);

    // staging source: wave wv's cluster, rows rs..rs+9 (contiguous 5 KB)
    const float* pS = yp + (size_t)(b * KK + wv) * CLS + (size_t)rs * WW + (size_t)L * 4;
    const float* pI = img + (size_t)b * CLS + (size_t)r * WW + c0;

    auto stage = [&](int t, int bi) {
        const float* g = pS + (size_t)t * PLANE;
        float* lb = &sbuf[bi][wv][0][0];     // wave-uniform; HW adds lane*16B
        #pragma unroll
        for (int i = 0; i < 5; i++) GLD(g + i * 256, lb + i * 256);  // 1KB = 2 rows each
    };

    auto extract = [&](int bi, int k, float4& m, float4& s9) {
        const float4 c  = *(const float4*)&sbuf[bi][k][sc][c0];
        const float4 u  = *(const float4*)&sbuf[bi][k][sm1][c0];
        const float4 dn = *(const float4*)&sbuf[bi][k][sp1][c0];
        m.x = c.x*c.x; m.y = c.y*c.y; m.z = c.z*c.z; m.w = c.w*c.w;
        float4 v;
        v.x = fmaf(u.x*u.x, su, fmaf(dn.x*dn.x, sd, m.x));
        v.y = fmaf(u.y*u.y, su, fmaf(dn.y*dn.y, sd, m.y));
        v.z = fmaf(u.z*u.z, su, fmaf(dn.z*dn.z, sd, m.z));
        v.w = fmaf(u.w*u.w, su, fmaf(dn.w*dn.w, sd, m.w));
        const float vl = okL ? __shfl_up(v.w, 1, 64)   : 0.f;
        const float vr = okR ? __shfl_down(v.x, 1, 64) : 0.f;
        const float t1 = v.x + v.y, t2 = v.z + v.w;
        s9.x = vl + t1; s9.y = t1 + v.z; s9.z = v.y + t2; s9.w = t2 + vr;
    };

    // ---- prolog ----
    stage((d0 > 0) ? d0 - 1 : 0, 1);
    WAIT_VM(0); BAR();                       // buf1 = plane d0-1 (all waves)

    float4 mp[KK], sp[KK];
    float4 Mp = make_float4(0.f,0.f,0.f,0.f), Sp = make_float4(0.f,0.f,0.f,0.f);
    #pragma unroll
    for (int k = 0; k < KK; k++) {
        extract(1, k, mp[k], sp[k]);
        Mp.x += mp[k].x; Mp.y += mp[k].y; Mp.z += mp[k].z; Mp.w += mp[k].w;
        Sp.x += sp[k].x; Sp.y += sp[k].y; Sp.z += sp[k].z; Sp.w += sp[k].w;
    }
    if (d0 == 0) {
        #pragma unroll
        for (int k = 0; k < KK; k++) {
            mp[k] = make_float4(0.f,0.f,0.f,0.f);
            sp[k] = make_float4(0.f,0.f,0.f,0.f);
        }
        Mp = make_float4(0.f,0.f,0.f,0.f); Sp = make_float4(0.f,0.f,0.f,0.f);
    }
    BAR();                                   // everyone done reading buf1

    float4 iv = *(const float4*)(pI + (size_t)d0 * PLANE);
    stage(d0, 0); stage(d0 + 1, 1);
    WAIT_VM(5); BAR();                       // buf0 ready; buf1's 5 in flight

    float smf[KK] = {0,0,0,0}, sif[KK] = {0,0,0,0}, saf[KK] = {0,0,0,0};
    float j2f = 0.f;

    auto cstep = [&](int bi, bool g) {
        const float4 iv2 = make_float4(iv.x*iv.x, iv.y*iv.y, iv.z*iv.z, iv.w*iv.w);
        float4 M = make_float4(0.f,0.f,0.f,0.f), S = make_float4(0.f,0.f,0.f,0.f);
        float q = 0.f, ctt = 0.f, ctp = 0.f, cpt = 0.f;
        #pragma unroll
        for (int k = 0; k < KK; k++) {
            float4 m, s9;
            extract(bi, k, m, s9);
            M.x += m.x;  M.y += m.y;  M.z += m.z;  M.w += m.w;
            S.x += s9.x; S.y += s9.y; S.z += s9.z; S.w += s9.w;
            q   = fmaf(m.x,m.x,     fmaf(m.y,m.y,     fmaf(m.z,m.z,     fmaf(m.w,m.w,     q))));
            ctt = fmaf(m.x,s9.x,    fmaf(m.y,s9.y,    fmaf(m.z,s9.z,    fmaf(m.w,s9.w,    ctt))));
            ctp = fmaf(m.x,sp[k].x, fmaf(m.y,sp[k].y, fmaf(m.z,sp[k].z, fmaf(m.w,sp[k].w, ctp))));
            if (g)
                cpt = fmaf(mp[k].x,s9.x, fmaf(mp[k].y,s9.y, fmaf(mp[k].z,s9.z, fmaf(mp[k].w,s9.w, cpt))));
            smf[k] += (m.x + m.y) + (m.z + m.w);
            sif[k] = fmaf(m.x,iv.x,  fmaf(m.y,iv.y,  fmaf(m.z,iv.z,  fmaf(m.w,iv.w,  sif[k]))));
            saf[k] = fmaf(m.x,iv2.x, fmaf(m.y,iv2.y, fmaf(m.z,iv2.z, fmaf(m.w,iv2.w, saf[k]))));
            mp[k] = m; sp[k] = s9;
        }
        j2f += (M.x*S.x + M.y*S.y + M.z*S.z + M.w*S.w)
             - (M.x*M.x + M.y*M.y + M.z*M.z + M.w*M.w)
             + q - ctt
             + (M.x*Sp.x + M.y*Sp.y + M.z*Sp.z + M.w*Sp.w) - ctp;
        if (g)
            j2f += (Mp.x*S.x + Mp.y*S.y + Mp.z*S.z + Mp.w*S.w) - cpt;
        Mp = M; Sp = S;
    };

    const bool E = (d0 + SD < DD);
    float4 ivn;

    // step 0 (t=d0, buf0)
    cstep(0, false);
    BAR();
    ivn = *(const float4*)(pI + (size_t)(d0 + 1) * PLANE);
    stage(d0 + 2, 0);
    WAIT_VM(5); BAR(); iv = ivn;             // buf1 (d0+1) ready; d0+2 in flight

    // step 1 (t=d0+1, buf1)
    cstep(1, true);
    BAR();
    ivn = *(const float4*)(pI + (size_t)(d0 + 2) * PLANE);
    stage(d0 + 3, 1);
    WAIT_VM(5); BAR(); iv = ivn;             // buf0 (d0+2) ready; d0+3 in flight

    // step 2 (t=d0+2, buf0)
    cstep(0, true);
    BAR();
    ivn = *(const float4*)(pI + (size_t)(d0 + 3) * PLANE);
    if (E) { stage(d0 + 4, 0); WAIT_VM(5); } else { WAIT_VM(0); }
    BAR(); iv = ivn;                         // buf1 (d0+3) ready

    // step 3 (t=d0+3, buf1)
    cstep(1, true);

    // epilog: next band for plane d0+SD (buf0)
    if (E) {
        WAIT_VM(0); BAR();                   // all waves' d0+4 GLDs landed
        float4 S = make_float4(0.f,0.f,0.f,0.f);
        float cpt = 0.f;
        #pragma unroll
        for (int k = 0; k < KK; k++) {
            float4 m, s9;
            extract(0, k, m, s9);
            S.x += s9.x; S.y += s9.y; S.z += s9.z; S.w += s9.w;
            cpt = fmaf(mp[k].x,s9.x, fmaf(mp[k].y,s9.y, fmaf(mp[k].z,s9.z, fmaf(mp[k].w,s9.w, cpt))));
        }
        j2f += (Mp.x*S.x + Mp.y*S.y + Mp.z*S.z + Mp.w*S.w) - cpt;
    }

    // ---- block reduction of 13 scalars (sbuf reused as scratch) ----
    double qd[13];
    #pragma unroll
    for (int k = 0; k < KK; k++) {
        qd[k] = (double)smf[k]; qd[4 + k] = (double)sif[k]; qd[8 + k] = (double)saf[k];
    }
    qd[12] = (double)j2f;

    #pragma unroll
    for (int qq = 0; qq < 13; qq++) {
        double v = qd[qq];
        #pragma unroll
        for (int off = 32; off > 0; off >>= 1) v += __shfl_down(v, off, 64);
        qd[qq] = v;
    }

    __syncthreads();                         // full drain OK here (end of kernel)
    double* red = (double*)&sbuf[0][0][0][0];
    if (L == 0) {
        #pragma unroll
        for (int qq = 0; qq < 13; qq++) red[wv * 13 + qq] = qd[qq];
    }
    __syncthreads();
    if (tid < 13) {
        const double sfin = red[tid] + red[13 + tid] + red[26 + tid] + red[39 + tid];
        int idxo;
        if      (tid < 4)  idxo = b * KK + tid;              // Sm
        else if (tid < 8)  idxo = 8  + b * KK + (tid - 4);   // Sim
        else if (tid < 12) idxo = 16 + b * KK + (tid - 8);   // A
        else               idxo = 24;                        // J2
        unsafeAtomicAdd(&ws[idxo], sfin);
    }
}

__global__ void rfcm_fin(const double* __restrict__ ws, float* __restrict__ out)
{
    if (threadIdx.x == 0 && blockIdx.x == 0) {
        double j1 = 0;
        #pragma unroll
        for (int i = 0; i < BB * KK; i++)
            j1 += ws[16 + i] - ws[8 + i] * ws[8 + i] / ws[i];
        const double invBN = 1.0 / ((double)BB * (double)DD * (double)HH * (double)WW);
        out[0] = (float)(j1 * invBN + 0.0008 * ws[24] * invBN);
    }
}

extern "C" void kernel_launch(void* const* d_in, const int* in_sizes, int n_in,
                              void* d_out, int out_size, void* d_ws, size_t ws_size,
                              hipStream_t stream) {
    const float* yp  = (const float*)d_in[0];   // y_pred [2,4,128,128,128]
    const float* img = (const float*)d_in[1];   // image  [2,1,128,128,128]
    float* out = (float*)d_out;
    double* ws = (double*)d_ws;

    hipMemsetAsync(d_ws, 0, 25 * sizeof(double), stream);

    dim3 grid(BB * NBD * NBH);   // 1024 blocks = 4/CU (40 KB LDS each)
    rfcm_main<<<grid, NT, 0, stream>>>(yp, img, ws);
    rfcm_fin<<<1, 64, 0, stream>>>(ws, out);
}

// Round 6
// 139.888 us; speedup vs baseline: 1.0291x; 1.0291x over previous
//
#include <hip/hip_runtime.h>

// RFCM loss, fused single pass + finalize. B=2, K=4, D=H=W=128. Scalar out.
//
// mean(J1) = (1/(B*N)) * sum_{b,k} [ A_bk - Sim_bk^2 / Sm_bk ]
//   Sm=sum mem, Sim=sum mem*img, A=sum mem*img^2, mem=y_pred^2
// mean(J2) = (1/(B*N)) * sum_n [ Sm*Sbk - Sm^2 - sum_k m*bk + sum_k m^2 ]
//   bk = box27(mem_k) incl center, zero pad. s9 = 3x3 in-plane box sum.
//   Per plane t: diag band (M_t*S_t - M_t^2 + q - ctt), prev band
//   (M_t*S_{t-1} - ctp), next band emitted one step late (M_{t-1}*S_t - cpt,
//   gated i>0; epilog adds it for plane d0+SD). Zero history at d0=0.
//
// R16 = R14 (session-best, 42.5us) + nontemporal staging loads. Session
// law: dur = FETCH / ~1.2 TB/s across 7 structural variants (occupancy
// 5-16 w/CU, LDS-DMA vs register, 8B vs 16B, depth 1-3, coop-LDS). Model:
// per-CU L1 read-path line-service wall (~MSHR x RTT); writes exempt
// (fill 6.5 TB/s), copy reads >3 TB/s (m13) => reads CAN go faster, the
// L1 path is the suspect. nt loads (__builtin_nontemporal_load -> global
// load with nt flag, compiler-scheduled) may bypass L1 allocation +
// tracking. Single-variable probe on the R14 skeleton.
// Pre-committed: 25-32us => real, chase occupancy; 42-45us null =>
// ROOFLINE next round; >=55us + FETCH>=120MB => thrash, revert+ROOFLINE.
// R15 lesson (58.9us): NO block-wide sync in the d-march, ever.
// NEVER __launch_bounds__ min-waves (R4/R6: VGPR=64 -> 240-330MB spills).

#define BB 2
#define KK 4
#define DD 128
#define HH 128
#define WW 128
#define PLANE (HH * WW)
#define CL (DD * PLANE)      // cluster stride (floats)
#define SD 8
#define NBD (DD / SD)        // 16
#define HR 8                 // rows/block = 4 waves x 2 rows
#define NBH (HH / HR)        // 16
#define NT 256

typedef float f4v __attribute__((ext_vector_type(4)));

__device__ __forceinline__ float4 ntload4(const float* p) {
    f4v v = __builtin_nontemporal_load((const f4v*)p);
    return make_float4(v.x, v.y, v.z, v.w);
}

__global__ __launch_bounds__(NT) void rfcm_main(
    const float* __restrict__ yp, const float* __restrict__ img,
    double* __restrict__ ws)
{
    __shared__ double red[4 * 13];   // 416 B reduction scratch

    const int tid  = threadIdx.x;
    const int wv   = tid >> 6;       // wave 0..3
    const int L    = tid & 63;
    const int half = L >> 5;         // 0: row rbase, 1: row rbase+1
    const int wl   = L & 31;
    const int c0   = wl << 2;        // 4 cols per lane

    // XCD swizzle: slab (b,dsb) -> XCD slab%8; its 16 h-tiles share one L2.
    const int bid  = blockIdx.x;
    const int xcd  = bid & 7;
    const int idx  = bid >> 3;       // 0..63
    const int sl   = idx >> 4;       // 0..3
    const int ht   = idx & 15;
    const int slab = sl * 8 + xcd;   // 0..31
    const int b    = slab >> 4;
    const int dsb  = slab & 15;

    const int rbase = ht * HR + (wv << 1);
    const int r     = rbase + half;            // own row
    const int d0    = dsb * SD;

    // halo row for this half (clamped + zero-scaled at volume edge)
    const int   gr  = half ? rbase + 2 : rbase - 1;
    const int   gH  = gr < 0 ? 0 : (gr > HH - 1 ? HH - 1 : gr);
    const float hsc = (gr >= 0 && gr <= HH - 1) ? 1.f : 0.f;

    const bool okL = (wl > 0), okR = (wl < 31);

    const float* pO = yp  + (size_t)(b * KK) * CL + (size_t)r  * WW + c0;
    const float* pH = yp  + (size_t)(b * KK) * CL + (size_t)gH * WW + c0;
    const float* pI = img + (size_t)b * CL        + (size_t)r  * WW + c0;

    // 3-deep plane ring: 4 clusters x (own4 + halo4) per slot
    float4 o0[KK], a0[KK], o1[KK], a1[KK], o2[KK], a2[KK];

    auto lplane = [&](int t, float4* o, float4* a) {
        const size_t tp = (size_t)t * PLANE;
        #pragma unroll
        for (int k = 0; k < KK; k++) {
            o[k] = ntload4(pO + (size_t)k * CL + tp);
            a[k] = ntload4(pH + (size_t)k * CL + tp);
        }
    };

    // (own,halo) raw -> center squares m + 3x3 box sum s9
    auto extract = [&](const float4 o4, const float4 a4, float4& m, float4& s9) {
        m.x = o4.x * o4.x; m.y = o4.y * o4.y;
        m.z = o4.z * o4.z; m.w = o4.w * o4.w;
        float4 v;
        v.x = m.x + __shfl_xor(m.x, 32, 64);   // partner half-wave row
        v.y = m.y + __shfl_xor(m.y, 32, 64);
        v.z = m.z + __shfl_xor(m.z, 32, 64);
        v.w = m.w + __shfl_xor(m.w, 32, 64);
        v.x = fmaf(a4.x * a4.x, hsc, v.x);     // halo row
        v.y = fmaf(a4.y * a4.y, hsc, v.y);
        v.z = fmaf(a4.z * a4.z, hsc, v.z);
        v.w = fmaf(a4.w * a4.w, hsc, v.w);
        const float vl = okL ? __shfl_up(v.w, 1, 64)   : 0.f;
        const float vr = okR ? __shfl_down(v.x, 1, 64) : 0.f;
        const float t1 = v.x + v.y, t2 = v.z + v.w;
        s9.x = vl + t1; s9.y = t1 + v.z; s9.z = v.y + t2; s9.w = t2 + vr;
    };

    // ---- prolog: 3 plane batches + img in flight before first wait ----
    lplane((d0 > 0) ? d0 - 1 : 0, o0, a0);
    lplane(d0,     o1, a1);
    lplane(d0 + 1, o2, a2);
    float4 iv = ntload4(pI + (size_t)d0 * PLANE);

    float4 mp[KK], sp[KK];
    float4 Mp = make_float4(0.f,0.f,0.f,0.f), Sp = make_float4(0.f,0.f,0.f,0.f);
    #pragma unroll
    for (int k = 0; k < KK; k++) {
        extract(o0[k], a0[k], mp[k], sp[k]);
        Mp.x += mp[k].x; Mp.y += mp[k].y; Mp.z += mp[k].z; Mp.w += mp[k].w;
        Sp.x += sp[k].x; Sp.y += sp[k].y; Sp.z += sp[k].z; Sp.w += sp[k].w;
    }
    if (d0 == 0) {   // no plane -1: zero history
        #pragma unroll
        for (int k = 0; k < KK; k++) {
            mp[k] = make_float4(0.f,0.f,0.f,0.f);
            sp[k] = make_float4(0.f,0.f,0.f,0.f);
        }
        Mp = make_float4(0.f,0.f,0.f,0.f); Sp = make_float4(0.f,0.f,0.f,0.f);
    }
    lplane(d0 + 2, o0, a0);          // d0+2 <= 122: always valid

    float smf[KK] = {0,0,0,0}, sif[KK] = {0,0,0,0}, saf[KK] = {0,0,0,0};
    float j2f = 0.f;

    // step i: consume plane t=d0+i from slot (i+1)%3; reload slot with t+3.
    auto step = [&](int i, float4* oS, float4* aS) {
        const int t = d0 + i;
        float4 ivn = iv;
        if (i < SD - 1) ivn = ntload4(pI + (size_t)(t + 1) * PLANE);
        const bool rel = (i <= SD - 3) && (t + 3 < DD);
        const size_t tp3 = (size_t)(t + 3) * PLANE;

        const float4 iv2 = make_float4(iv.x*iv.x, iv.y*iv.y, iv.z*iv.z, iv.w*iv.w);
        float4 M = make_float4(0.f,0.f,0.f,0.f), S = make_float4(0.f,0.f,0.f,0.f);
        float q = 0.f, ctt = 0.f, ctp = 0.f, cpt = 0.f;

        #pragma unroll
        for (int k = 0; k < KK; k++) {
            float4 m, s9;
            extract(oS[k], aS[k], m, s9);
            if (rel) {                       // reload freed slot with t+3
                oS[k] = ntload4(pO + (size_t)k * CL + tp3);
                aS[k] = ntload4(pH + (size_t)k * CL + tp3);
            }
            M.x += m.x;  M.y += m.y;  M.z += m.z;  M.w += m.w;
            S.x += s9.x; S.y += s9.y; S.z += s9.z; S.w += s9.w;
            q   = fmaf(m.x,m.x,     fmaf(m.y,m.y,     fmaf(m.z,m.z,     fmaf(m.w,m.w,     q))));
            ctt = fmaf(m.x,s9.x,    fmaf(m.y,s9.y,    fmaf(m.z,s9.z,    fmaf(m.w,s9.w,    ctt))));
            ctp = fmaf(m.x,sp[k].x, fmaf(m.y,sp[k].y, fmaf(m.z,sp[k].z, fmaf(m.w,sp[k].w, ctp))));
            if (i > 0)
                cpt = fmaf(mp[k].x,s9.x, fmaf(mp[k].y,s9.y, fmaf(mp[k].z,s9.z, fmaf(mp[k].w,s9.w, cpt))));
            smf[k] += (m.x + m.y) + (m.z + m.w);
            sif[k] = fmaf(m.x,iv.x,  fmaf(m.y,iv.y,  fmaf(m.z,iv.z,  fmaf(m.w,iv.w,  sif[k]))));
            saf[k] = fmaf(m.x,iv2.x, fmaf(m.y,iv2.y, fmaf(m.z,iv2.z, fmaf(m.w,iv2.w, saf[k]))));
            mp[k] = m; sp[k] = s9;
        }

        j2f += (M.x*S.x + M.y*S.y + M.z*S.z + M.w*S.w)
             - (M.x*M.x + M.y*M.y + M.z*M.z + M.w*M.w)
             + q - ctt
             + (M.x*Sp.x + M.y*Sp.y + M.z*Sp.z + M.w*Sp.w) - ctp;
        if (i > 0)
            j2f += (Mp.x*S.x + Mp.y*S.y + Mp.z*S.z + Mp.w*S.w) - cpt;

        Mp = M; Sp = S;
        iv = ivn;
    };

    step(0, o1, a1); step(1, o2, a2); step(2, o0, a0);
    step(3, o1, a1); step(4, o2, a2); step(5, o0, a0);
    step(6, o1, a1); step(7, o2, a2);

    // epilog: next-band for plane d0+SD (slot 0; skipped at volume edge)
    if (d0 + SD < DD) {
        float4 S = make_float4(0.f,0.f,0.f,0.f);
        float cpt = 0.f;
        #pragma unroll
        for (int k = 0; k < KK; k++) {
            float4 m, s9;
            extract(o0[k], a0[k], m, s9);
            S.x += s9.x; S.y += s9.y; S.z += s9.z; S.w += s9.w;
            cpt = fmaf(mp[k].x,s9.x, fmaf(mp[k].y,s9.y, fmaf(mp[k].z,s9.z, fmaf(mp[k].w,s9.w, cpt))));
        }
        j2f += (Mp.x*S.x + Mp.y*S.y + Mp.z*S.z + Mp.w*S.w) - cpt;
    }

    // ---- block reduction of 13 scalars ----
    double qd[13];
    #pragma unroll
    for (int k = 0; k < KK; k++) {
        qd[k] = (double)smf[k]; qd[4 + k] = (double)sif[k]; qd[8 + k] = (double)saf[k];
    }
    qd[12] = (double)j2f;

    #pragma unroll
    for (int qq = 0; qq < 13; qq++) {
        double v = qd[qq];
        #pragma unroll
        for (int off = 32; off > 0; off >>= 1) v += __shfl_down(v, off, 64);
        qd[qq] = v;
    }

    const int lane = tid & 63, wid = tid >> 6;
    if (lane == 0) {
        #pragma unroll
        for (int qq = 0; qq < 13; qq++) red[wid * 13 + qq] = qd[qq];
    }
    __syncthreads();
    if (tid < 13) {
        const double sfin = red[tid] + red[13 + tid] + red[26 + tid] + red[39 + tid];
        int idxo;
        if      (tid < 4)  idxo = b * KK + tid;              // Sm
        else if (tid < 8)  idxo = 8  + b * KK + (tid - 4);   // Sim
        else if (tid < 12) idxo = 16 + b * KK + (tid - 8);   // A
        else               idxo = 24;                        // J2
        unsafeAtomicAdd(&ws[idxo], sfin);
    }
}

__global__ void rfcm_fin(const double* __restrict__ ws, float* __restrict__ out)
{
    if (threadIdx.x == 0 && blockIdx.x == 0) {
        double j1 = 0;
        #pragma unroll
        for (int i = 0; i < BB * KK; i++)
            j1 += ws[16 + i] - ws[8 + i] * ws[8 + i] / ws[i];
        const double invBN = 1.0 / ((double)BB * (double)DD * (double)HH * (double)WW);
        out[0] = (float)(j1 * invBN + 0.0008 * ws[24] * invBN);
    }
}

extern "C" void kernel_launch(void* const* d_in, const int* in_sizes, int n_in,
                              void* d_out, int out_size, void* d_ws, size_t ws_size,
                              hipStream_t stream) {
    const float* yp  = (const float*)d_in[0];   // y_pred [2,4,128,128,128]
    const float* img = (const float*)d_in[1];   // image  [2,1,128,128,128]
    float* out = (float*)d_out;
    double* ws = (double*)d_ws;

    hipMemsetAsync(d_ws, 0, 25 * sizeof(double), stream);

    dim3 grid(BB * NBD * NBH);   // 512 blocks, 2/CU
    rfcm_main<<<grid, NT, 0, stream>>>(yp, img, ws);
    rfcm_fin<<<1, 64, 0, stream>>>(ws, out);
}

// Round 7
// 126.963 us; speedup vs baseline: 1.1338x; 1.1018x over previous
//
#include <hip/hip_runtime.h>

// RFCM loss, fused single pass + finalize. B=2, K=4, D=H=W=128. Scalar out.
//
// mean(J1) = (1/(B*N)) * sum_{b,k} [ A_bk - Sim_bk^2 / Sm_bk ]
//   Sm=sum mem, Sim=sum mem*img, A=sum mem*img^2, mem=y_pred^2
// mean(J2) = (1/(B*N)) * sum_n [ Sm*Sbk - Sm^2 - sum_k m*bk + sum_k m^2 ]
//   bk = box27(mem_k) incl center, zero pad. s9 = 3x3 in-plane box sum.
//   Per plane t: diag band (M_t*S_t - M_t^2 + q - ctt), prev band
//   (M_t*S_{t-1} - ctp), next band emitted one step late (M_{t-1}*S_t - cpt,
//   gated i>0; epilog adds it for plane d0+SD). Zero history at d0=0.
//
// R17 = R14 verbatim (session-best, 42.5us main) -- pre-committed revert
// after the R16 nt-load probe returned null (46.6-47.7us, FETCH ~53MB:
// the L1-policy lever does not move the wall). FINAL session model, held
// over 8 structural variants: dur = FETCH / ~1.2 TB/s read-service rate,
// invariant to occupancy (5-16 w/CU), staging (LDS-DMA vs reg), width
// (8B vs 16B), depth (1-3), coop-dedup (barrier cost > dedup win, R15),
// nt flags (null, R16). Floor arithmetic: ~49.7MB compulsory fetch (J2
// stencil coupling; inter-iteration state cold -- harness's 268MB fills
// thrash L3) / 1.2 TB/s = ~41us. R10 (LDS-DMA) and R14 (reg-ring) tie at
// 42.5/42.6 => structural floor reached; ROOFLINE after reproduction.
// R15 lesson: NO block-wide sync in the d-march, ever.
// NEVER __launch_bounds__ min-waves (R4/R6: VGPR=64 -> 240-330MB spills).

#define BB 2
#define KK 4
#define DD 128
#define HH 128
#define WW 128
#define PLANE (HH * WW)
#define CL (DD * PLANE)      // cluster stride (floats)
#define SD 8
#define NBD (DD / SD)        // 16
#define HR 8                 // rows/block = 4 waves x 2 rows
#define NBH (HH / HR)        // 16
#define NT 256

__global__ __launch_bounds__(NT) void rfcm_main(
    const float* __restrict__ yp, const float* __restrict__ img,
    double* __restrict__ ws)
{
    __shared__ double red[4 * 13];   // 416 B reduction scratch

    const int tid  = threadIdx.x;
    const int wv   = tid >> 6;       // wave 0..3
    const int L    = tid & 63;
    const int half = L >> 5;         // 0: row rbase, 1: row rbase+1
    const int wl   = L & 31;
    const int c0   = wl << 2;        // 4 cols per lane

    // XCD swizzle: slab (b,dsb) -> XCD slab%8; its 16 h-tiles share one L2.
    const int bid  = blockIdx.x;
    const int xcd  = bid & 7;
    const int idx  = bid >> 3;       // 0..63
    const int sl   = idx >> 4;       // 0..3
    const int ht   = idx & 15;
    const int slab = sl * 8 + xcd;   // 0..31
    const int b    = slab >> 4;
    const int dsb  = slab & 15;

    const int rbase = ht * HR + (wv << 1);
    const int r     = rbase + half;            // own row
    const int d0    = dsb * SD;

    // halo row for this half (clamped + zero-scaled at volume edge)
    const int   gr  = half ? rbase + 2 : rbase - 1;
    const int   gH  = gr < 0 ? 0 : (gr > HH - 1 ? HH - 1 : gr);
    const float hsc = (gr >= 0 && gr <= HH - 1) ? 1.f : 0.f;

    const bool okL = (wl > 0), okR = (wl < 31);

    const float* pO = yp  + (size_t)(b * KK) * CL + (size_t)r  * WW + c0;
    const float* pH = yp  + (size_t)(b * KK) * CL + (size_t)gH * WW + c0;
    const float* pI = img + (size_t)b * CL        + (size_t)r  * WW + c0;

    // 3-deep plane ring: 4 clusters x (own4 + halo4) per slot
    float4 o0[KK], a0[KK], o1[KK], a1[KK], o2[KK], a2[KK];

    auto lplane = [&](int t, float4* o, float4* a) {
        const size_t tp = (size_t)t * PLANE;
        #pragma unroll
        for (int k = 0; k < KK; k++) {
            o[k] = *(const float4*)(pO + (size_t)k * CL + tp);
            a[k] = *(const float4*)(pH + (size_t)k * CL + tp);
        }
    };

    // (own,halo) raw -> center squares m + 3x3 box sum s9
    auto extract = [&](const float4 o4, const float4 a4, float4& m, float4& s9) {
        m.x = o4.x * o4.x; m.y = o4.y * o4.y;
        m.z = o4.z * o4.z; m.w = o4.w * o4.w;
        float4 v;
        v.x = m.x + __shfl_xor(m.x, 32, 64);   // partner half-wave row
        v.y = m.y + __shfl_xor(m.y, 32, 64);
        v.z = m.z + __shfl_xor(m.z, 32, 64);
        v.w = m.w + __shfl_xor(m.w, 32, 64);
        v.x = fmaf(a4.x * a4.x, hsc, v.x);     // halo row
        v.y = fmaf(a4.y * a4.y, hsc, v.y);
        v.z = fmaf(a4.z * a4.z, hsc, v.z);
        v.w = fmaf(a4.w * a4.w, hsc, v.w);
        const float vl = okL ? __shfl_up(v.w, 1, 64)   : 0.f;
        const float vr = okR ? __shfl_down(v.x, 1, 64) : 0.f;
        const float t1 = v.x + v.y, t2 = v.z + v.w;
        s9.x = vl + t1; s9.y = t1 + v.z; s9.z = v.y + t2; s9.w = t2 + vr;
    };

    // ---- prolog: 3 plane batches + img in flight before first wait ----
    lplane((d0 > 0) ? d0 - 1 : 0, o0, a0);
    lplane(d0,     o1, a1);
    lplane(d0 + 1, o2, a2);
    float4 iv = *(const float4*)(pI + (size_t)d0 * PLANE);

    float4 mp[KK], sp[KK];
    float4 Mp = make_float4(0.f,0.f,0.f,0.f), Sp = make_float4(0.f,0.f,0.f,0.f);
    #pragma unroll
    for (int k = 0; k < KK; k++) {
        extract(o0[k], a0[k], mp[k], sp[k]);
        Mp.x += mp[k].x; Mp.y += mp[k].y; Mp.z += mp[k].z; Mp.w += mp[k].w;
        Sp.x += sp[k].x; Sp.y += sp[k].y; Sp.z += sp[k].z; Sp.w += sp[k].w;
    }
    if (d0 == 0) {   // no plane -1: zero history
        #pragma unroll
        for (int k = 0; k < KK; k++) {
            mp[k] = make_float4(0.f,0.f,0.f,0.f);
            sp[k] = make_float4(0.f,0.f,0.f,0.f);
        }
        Mp = make_float4(0.f,0.f,0.f,0.f); Sp = make_float4(0.f,0.f,0.f,0.f);
    }
    lplane(d0 + 2, o0, a0);          // d0+2 <= 122: always valid

    float smf[KK] = {0,0,0,0}, sif[KK] = {0,0,0,0}, saf[KK] = {0,0,0,0};
    float j2f = 0.f;

    // step i: consume plane t=d0+i from slot (i+1)%3; reload slot with t+3.
    auto step = [&](int i, float4* oS, float4* aS) {
        const int t = d0 + i;
        float4 ivn = iv;
        if (i < SD - 1) ivn = *(const float4*)(pI + (size_t)(t + 1) * PLANE);
        const bool rel = (i <= SD - 3) && (t + 3 < DD);
        const size_t tp3 = (size_t)(t + 3) * PLANE;

        const float4 iv2 = make_float4(iv.x*iv.x, iv.y*iv.y, iv.z*iv.z, iv.w*iv.w);
        float4 M = make_float4(0.f,0.f,0.f,0.f), S = make_float4(0.f,0.f,0.f,0.f);
        float q = 0.f, ctt = 0.f, ctp = 0.f, cpt = 0.f;

        #pragma unroll
        for (int k = 0; k < KK; k++) {
            float4 m, s9;
            extract(oS[k], aS[k], m, s9);
            if (rel) {                       // reload freed slot with t+3
                oS[k] = *(const float4*)(pO + (size_t)k * CL + tp3);
                aS[k] = *(const float4*)(pH + (size_t)k * CL + tp3);
            }
            M.x += m.x;  M.y += m.y;  M.z += m.z;  M.w += m.w;
            S.x += s9.x; S.y += s9.y; S.z += s9.z; S.w += s9.w;
            q   = fmaf(m.x,m.x,     fmaf(m.y,m.y,     fmaf(m.z,m.z,     fmaf(m.w,m.w,     q))));
            ctt = fmaf(m.x,s9.x,    fmaf(m.y,s9.y,    fmaf(m.z,s9.z,    fmaf(m.w,s9.w,    ctt))));
            ctp = fmaf(m.x,sp[k].x, fmaf(m.y,sp[k].y, fmaf(m.z,sp[k].z, fmaf(m.w,sp[k].w, ctp))));
            if (i > 0)
                cpt = fmaf(mp[k].x,s9.x, fmaf(mp[k].y,s9.y, fmaf(mp[k].z,s9.z, fmaf(mp[k].w,s9.w, cpt))));
            smf[k] += (m.x + m.y) + (m.z + m.w);
            sif[k] = fmaf(m.x,iv.x,  fmaf(m.y,iv.y,  fmaf(m.z,iv.z,  fmaf(m.w,iv.w,  sif[k]))));
            saf[k] = fmaf(m.x,iv2.x, fmaf(m.y,iv2.y, fmaf(m.z,iv2.z, fmaf(m.w,iv2.w, saf[k]))));
            mp[k] = m; sp[k] = s9;
        }

        j2f += (M.x*S.x + M.y*S.y + M.z*S.z + M.w*S.w)
             - (M.x*M.x + M.y*M.y + M.z*M.z + M.w*M.w)
             + q - ctt
             + (M.x*Sp.x + M.y*Sp.y + M.z*Sp.z + M.w*Sp.w) - ctp;
        if (i > 0)
            j2f += (Mp.x*S.x + Mp.y*S.y + Mp.z*S.z + Mp.w*S.w) - cpt;

        Mp = M; Sp = S;
        iv = ivn;
    };

    step(0, o1, a1); step(1, o2, a2); step(2, o0, a0);
    step(3, o1, a1); step(4, o2, a2); step(5, o0, a0);
    step(6, o1, a1); step(7, o2, a2);

    // epilog: next-band for plane d0+SD (slot 0; skipped at volume edge)
    if (d0 + SD < DD) {
        float4 S = make_float4(0.f,0.f,0.f,0.f);
        float cpt = 0.f;
        #pragma unroll
        for (int k = 0; k < KK; k++) {
            float4 m, s9;
            extract(o0[k], a0[k], m, s9);
            S.x += s9.x; S.y += s9.y; S.z += s9.z; S.w += s9.w;
            cpt = fmaf(mp[k].x,s9.x, fmaf(mp[k].y,s9.y, fmaf(mp[k].z,s9.z, fmaf(mp[k].w,s9.w, cpt))));
        }
        j2f += (Mp.x*S.x + Mp.y*S.y + Mp.z*S.z + Mp.w*S.w) - cpt;
    }

    // ---- block reduction of 13 scalars ----
    double qd[13];
    #pragma unroll
    for (int k = 0; k < KK; k++) {
        qd[k] = (double)smf[k]; qd[4 + k] = (double)sif[k]; qd[8 + k] = (double)saf[k];
    }
    qd[12] = (double)j2f;

    #pragma unroll
    for (int qq = 0; qq < 13; qq++) {
        double v = qd[qq];
        #pragma unroll
        for (int off = 32; off > 0; off >>= 1) v += __shfl_down(v, off, 64);
        qd[qq] = v;
    }

    const int lane = tid & 63, wid = tid >> 6;
    if (lane == 0) {
        #pragma unroll
        for (int qq = 0; qq < 13; qq++) red[wid * 13 + qq] = qd[qq];
    }
    __syncthreads();
    if (tid < 13) {
        const double sfin = red[tid] + red[13 + tid] + red[26 + tid] + red[39 + tid];
        int idxo;
        if      (tid < 4)  idxo = b * KK + tid;              // Sm
        else if (tid < 8)  idxo = 8  + b * KK + (tid - 4);   // Sim
        else if (tid < 12) idxo = 16 + b * KK + (tid - 8);   // A
        else               idxo = 24;                        // J2
        unsafeAtomicAdd(&ws[idxo], sfin);
    }
}

__global__ void rfcm_fin(const double* __restrict__ ws, float* __restrict__ out)
{
    if (threadIdx.x == 0 && blockIdx.x == 0) {
        double j1 = 0;
        #pragma unroll
        for (int i = 0; i < BB * KK; i++)
            j1 += ws[16 + i] - ws[8 + i] * ws[8 + i] / ws[i];
        const double invBN = 1.0 / ((double)BB * (double)DD * (double)HH * (double)WW);
        out[0] = (float)(j1 * invBN + 0.0008 * ws[24] * invBN);
    }
}

extern "C" void kernel_launch(void* const* d_in, const int* in_sizes, int n_in,
                              void* d_out, int out_size, void* d_ws, size_t ws_size,
                              hipStream_t stream) {
    const float* yp  = (const float*)d_in[0];   // y_pred [2,4,128,128,128]
    const float* img = (const float*)d_in[1];   // image  [2,1,128,128,128]
    float* out = (float*)d_out;
    double* ws = (double*)d_ws;

    hipMemsetAsync(d_ws, 0, 25 * sizeof(double), stream);

    dim3 grid(BB * NBD * NBH);   // 512 blocks, 2/CU
    rfcm_main<<<grid, NT, 0, stream>>>(yp, img, ws);
    rfcm_fin<<<1, 64, 0, stream>>>(ws, out);
}